// Round 1
// baseline (202.226 us; speedup 1.0000x reference)
//
#include <hip/hip_runtime.h>

#define NUM_BINS 1025
#define NBLK 2048
#define BLOCK 256

// Stage 1: per-block signed LDS histogram (+origin, -pre), flushed to d_ws.
__global__ __launch_bounds__(BLOCK) void hist_kernel(
    const float* __restrict__ od, const int* __restrict__ om,
    const float* __restrict__ pd, const int* __restrict__ nm,
    float* __restrict__ partial, int n)
{
    __shared__ float lh[NUM_BINS];
    const int tid = threadIdx.x;
    for (int b = tid; b < NUM_BINS; b += BLOCK) lh[b] = 0.0f;
    __syncthreads();

    const int n4 = n >> 2;
    const float4* od4 = (const float4*)od;
    const int4*   om4 = (const int4*)om;
    const float4* pd4 = (const float4*)pd;
    const int4*   nm4 = (const int4*)nm;

    const int stride = gridDim.x * BLOCK;
    for (int i = blockIdx.x * BLOCK + tid; i < n4; i += stride) {
        float4 d = od4[i]; int4 m = om4[i];
        atomicAdd(&lh[m.x], d.x);
        atomicAdd(&lh[m.y], d.y);
        atomicAdd(&lh[m.z], d.z);
        atomicAdd(&lh[m.w], d.w);
        float4 e = pd4[i]; int4 q = nm4[i];
        atomicAdd(&lh[q.x], -e.x);
        atomicAdd(&lh[q.y], -e.y);
        atomicAdd(&lh[q.z], -e.z);
        atomicAdd(&lh[q.w], -e.w);
    }
    // scalar tail (n % 4), normally empty for 4096x4096
    if (blockIdx.x == 0 && tid == 0) {
        for (int i = n4 << 2; i < n; ++i) {
            atomicAdd(&lh[om[i]], od[i]);
            atomicAdd(&lh[nm[i]], -pd[i]);
        }
    }
    __syncthreads();

    float* row = partial + (size_t)blockIdx.x * NUM_BINS;
    for (int b = tid; b < NUM_BINS; b += BLOCK) row[b] = lh[b];
}

// Stage 2: one block per bin; sum partials over blocks, |.|, atomicAdd to out.
__global__ __launch_bounds__(256) void reduce_kernel(
    const float* __restrict__ partial, float* __restrict__ out, int nblk)
{
    const int b = blockIdx.x;           // bin index
    float s = 0.0f;
    for (int k = threadIdx.x; k < nblk; k += 256)
        s += partial[(size_t)k * NUM_BINS + b];

    // wave64 reduce
    for (int off = 32; off > 0; off >>= 1)
        s += __shfl_down(s, off, 64);

    __shared__ float wsum[4];
    const int wave = threadIdx.x >> 6;
    const int lane = threadIdx.x & 63;
    if (lane == 0) wsum[wave] = s;
    __syncthreads();
    if (threadIdx.x == 0) {
        float t = wsum[0] + wsum[1] + wsum[2] + wsum[3];
        atomicAdd(out, fabsf(t));
    }
}

extern "C" void kernel_launch(void* const* d_in, const int* in_sizes, int n_in,
                              void* d_out, int out_size, void* d_ws, size_t ws_size,
                              hipStream_t stream) {
    const float* od = (const float*)d_in[0];   // origin_density
    const int*   om = (const int*)d_in[1];     // origin_mask
    const float* pd = (const float*)d_in[2];   // pre_density
    const int*   nm = (const int*)d_in[3];     // new_mask
    float* out = (float*)d_out;
    float* partial = (float*)d_ws;
    const int n = in_sizes[0];

    int nblk = NBLK;
    size_t need = (size_t)nblk * NUM_BINS * sizeof(float);
    if (need > ws_size) {
        nblk = (int)(ws_size / (NUM_BINS * sizeof(float)));
        if (nblk < 1) nblk = 1;
    }

    hipMemsetAsync(d_out, 0, sizeof(float), stream);
    hist_kernel<<<nblk, BLOCK, 0, stream>>>(od, om, pd, nm, partial, n);
    reduce_kernel<<<NUM_BINS, 256, 0, stream>>>(partial, out, nblk);
}